// Round 15
// baseline (192.964 us; speedup 1.0000x reference)
//
#include <hip/hip_runtime.h>
#include <hip/hip_bf16.h>
#include <stdint.h>

// MHSA: B=4, N=8192, C=512, HEADS=8, d=64.
// R15: R14 (fused x f32->bf16 into QKV staging) with the macro token-paste
// bug fixed: staging regs are float4 arrays with constant indices.
// QKV A-path: f32 loads (pre-swizzled source) -> pk2 -> ds_write_b128;
// B stays global_load_lds. FC keeps the R13 DMA path. Sync per step:
// vmcnt(0)+lgkmcnt(0) -> barrier -> issue stage(s+2) -> frag reads(s+1)
// interleaved with MFMA(s) -> cvt+ds_write A(s+2).

typedef __bf16 bf16x8 __attribute__((ext_vector_type(8)));
typedef float f32x4 __attribute__((ext_vector_type(4)));

__device__ __forceinline__ unsigned short f2bf(float f) {
  unsigned u = __float_as_uint(f);
  u += 0x7fffu + ((u >> 16) & 1u);  // RNE
  return (unsigned short)(u >> 16);
}
__device__ __forceinline__ unsigned pk2(float a, float b) {
  return (unsigned)f2bf(a) | ((unsigned)f2bf(b) << 16);
}
__device__ __forceinline__ void unpk2(unsigned u, float& a, float& b) {
  a = __uint_as_float(u << 16);
  b = __uint_as_float(u & 0xffff0000u);
}
__device__ __forceinline__ void gload_lds16(const void* g, void* l) {
  __builtin_amdgcn_global_load_lds((const __attribute__((address_space(1))) void*)g,
                                   (__attribute__((address_space(3))) void*)l,
                                   16, 0, 0);
}

// ---------------- weights f32 -> bf16 convert (w_qkv + w_fc only) ----------------
__global__ __launch_bounds__(256) void cvt_w(const float* __restrict__ wq,
                                             const float* __restrict__ wf,
                                             unsigned short* __restrict__ wqb,
                                             unsigned short* __restrict__ wfb) {
  const int n1 = 98304;  // 1536*512/8
  int i = blockIdx.x * 256 + threadIdx.x;
  const float* in;
  unsigned short* ob;
  int j;
  if (i < n1) {
    in = wq; ob = wqb; j = i;
  } else {
    in = wf; ob = wfb; j = i - n1;
  }
  const float4* p = (const float4*)in;
  float4 a = p[j * 2];
  float4 b = p[j * 2 + 1];
  uint4 o;
  o.x = pk2(a.x, a.y);
  o.y = pk2(a.z, a.w);
  o.z = pk2(b.x, b.y);
  o.w = pk2(b.z, b.w);
  ((uint4*)ob)[j] = o;
}

// ---------------- 256x128 pipelined GEMM, C = A @ B^T + bias ----------------
// 8 waves (4M x 2N, wave-tile 64x64), 16x16x32 MFMA, 3 x 24 KiB LDS buffers.
// Region swizzle: phys(row,kg) = (row>>1)*128 + ((((row&1)<<2)|kg)^((row>>1)&7))*16.
// AF32: A source is f32, staged via regs + pk2 + ds_write (fused convert).

#define STG_A_DMA(S, BUF)                                                                 \
  do {                                                                                    \
    int _k0 = (S) * 32;                                                                   \
    gload_lds16(Ab + (size_t)(bm0 + srowA0) * KDIM + _k0 + skofA0,                        \
                lds + (BUF) * 24576 + dstA0);                                             \
    gload_lds16(Ab + (size_t)(bm0 + srowA1) * KDIM + _k0 + skofA1,                        \
                lds + (BUF) * 24576 + dstA1);                                             \
  } while (0)

#define STG_B(S, BUF)                                                                     \
  gload_lds16(Bg + (size_t)(bn0 + srowB) * KDIM + (S) * 32 + skofB,                       \
              lds + (BUF) * 24576 + 16384 + dstB)

#define ISSUE_A(S, RG)                                                                    \
  do {                                                                                    \
    int _k0 = (S) * 32;                                                                   \
    const float* _p0 = Af + (size_t)(bm0 + srowA0) * KDIM + _k0 + skofA0;                 \
    const float* _p1 = Af + (size_t)(bm0 + srowA1) * KDIM + _k0 + skofA1;                 \
    RG[0] = *(const float4*)(_p0);                                                        \
    RG[1] = *(const float4*)(_p0 + 4);                                                    \
    RG[2] = *(const float4*)(_p1);                                                        \
    RG[3] = *(const float4*)(_p1 + 4);                                                    \
  } while (0)

#define WRITE_A(S, RG)                                                                    \
  do {                                                                                    \
    uint4 _w0{pk2(RG[0].x, RG[0].y), pk2(RG[0].z, RG[0].w),                               \
              pk2(RG[1].x, RG[1].y), pk2(RG[1].z, RG[1].w)};                              \
    uint4 _w1{pk2(RG[2].x, RG[2].y), pk2(RG[2].z, RG[2].w),                               \
              pk2(RG[3].x, RG[3].y), pk2(RG[3].z, RG[3].w)};                              \
    *(uint4*)(lds + ((S) % 3) * 24576 + dstA0 + ln * 16) = _w0;                           \
    *(uint4*)(lds + ((S) % 3) * 24576 + dstA1 + ln * 16) = _w1;                           \
  } while (0)

#define STEP(S, BC, BN)                                                                   \
  do {                                                                                    \
    const int s_ = (S);                                                                   \
    asm volatile("s_waitcnt vmcnt(0) lgkmcnt(0)" ::: "memory"); /* own certs */           \
    __builtin_amdgcn_s_barrier();                               /* all certified */       \
    __builtin_amdgcn_sched_barrier(0);                                                    \
    if (s_ + 2 < NKT) {                                                                   \
      if constexpr (AF32) {                                                               \
        ISSUE_A(s_ + 2, rgl);                                                             \
      } else {                                                                            \
        STG_A_DMA(s_ + 2, (s_ + 2) % 3);                                                  \
      }                                                                                   \
      STG_B(s_ + 2, (s_ + 2) % 3);                                                        \
    }                                                                                     \
    const char* nab = lds + ((s_ + 1) % 3) * 24576 + wm * 4096 + pbase;                   \
    const char* nbb = lds + ((s_ + 1) % 3) * 24576 + 16384 + wn * 4096 + pbase;           \
    if (s_ + 1 < NKT) {                                                                   \
      BN[0] = *(const bf16x8*)(nbb);                                                      \
      BN[1] = *(const bf16x8*)(nbb + 1024);                                               \
      BN[2] = *(const bf16x8*)(nbb + 2048);                                               \
      BN[3] = *(const bf16x8*)(nbb + 3072);                                               \
    }                                                                                     \
    __builtin_amdgcn_s_setprio(1);                                                        \
    _Pragma("unroll") for (int _i = 0; _i < 4; ++_i) {                                    \
      acc[_i][0] = __builtin_amdgcn_mfma_f32_16x16x32_bf16(af[_i], BC[0], acc[_i][0], 0, 0, 0); \
      acc[_i][1] = __builtin_amdgcn_mfma_f32_16x16x32_bf16(af[_i], BC[1], acc[_i][1], 0, 0, 0); \
      acc[_i][2] = __builtin_amdgcn_mfma_f32_16x16x32_bf16(af[_i], BC[2], acc[_i][2], 0, 0, 0); \
      acc[_i][3] = __builtin_amdgcn_mfma_f32_16x16x32_bf16(af[_i], BC[3], acc[_i][3], 0, 0, 0); \
      if (s_ + 1 < NKT) af[_i] = *(const bf16x8*)(nab + _i * 1024);                       \
    }                                                                                     \
    __builtin_amdgcn_s_setprio(0);                                                        \
    if constexpr (AF32) {                                                                 \
      if (s_ + 2 < NKT) WRITE_A(s_ + 2, rgl); /* reg-dep waits auto-inserted */           \
    }                                                                                     \
  } while (0)

template <bool OUT_BF16, int KDIM, bool AF32>
__global__ __launch_bounds__(512, 4) void gemmp(const void* __restrict__ Ag_,
                                                const __hip_bfloat16* __restrict__ Bg,
                                                const float* __restrict__ bias,
                                                void* __restrict__ C,
                                                int M, int N, int NT) {
  __shared__ __align__(16) char lds[73728];

  const float* Af = (const float*)Ag_;
  const __hip_bfloat16* Ab = (const __hip_bfloat16*)Ag_;

  const int tid = threadIdx.x;
  const int wv = tid >> 6;
  const int ln = tid & 63;
  const int lrow = ln & 15;
  const int kg = ln >> 4;
  const int wm = wv >> 1;  // 0..3 -> 64-row panel
  const int wn = wv & 1;   // 0..1 -> 64-col panel

  // XCD-aware bijective swizzle (gridDim.x % 8 == 0)
  int nwg = gridDim.x;
  int cpx = nwg >> 3;
  int bs = (blockIdx.x & 7) * cpx + (blockIdx.x >> 3);
  const int bm0 = (bs / NT) * 256;
  const int bn0 = (bs % NT) * 128;

  const int pbase = (lrow >> 1) * 128 + ((((lrow & 1) << 2) | kg) ^ ((lrow >> 1) & 7)) * 16;

  // staging maps (pre-swizzled source, linear LDS dest)
  int srowA0, skofA0, dstA0, srowA1, skofA1, dstA1, srowB, skofB, dstB;
  {
    int L0 = wv * 1024 + ln * 16;
    int rp0 = L0 >> 7, T0 = ((L0 >> 4) & 7) ^ (rp0 & 7);
    srowA0 = rp0 * 2 + (T0 >> 2);
    skofA0 = (T0 & 3) * 8;
    dstA0 = wv * 1024;
    int L1 = 8192 + L0;
    int rp1 = L1 >> 7, T1 = ((L1 >> 4) & 7) ^ (rp1 & 7);
    srowA1 = rp1 * 2 + (T1 >> 2);
    skofA1 = (T1 & 3) * 8;
    dstA1 = 8192 + wv * 1024;
    srowB = srowA0;
    skofB = skofA0;
    dstB = wv * 1024;
  }

  f32x4 acc[4][4] = {};
  bf16x8 af[4], bs0[4], bs1[4];
  float4 rgl[4], rp[4];  // A-staging regs (AF32); constant indices only

  constexpr int NKT = KDIM >> 5;  // 16 for K=512

  // ---- prologue: stage tiles 0,1 ----
  if constexpr (AF32) {
    ISSUE_A(0, rgl);
    STG_B(0, 0);
    ISSUE_A(1, rp);
    STG_B(1, 1);
    WRITE_A(0, rgl);  // auto reg-dep waits
    WRITE_A(1, rp);
    asm volatile("s_waitcnt vmcnt(0) lgkmcnt(0)" ::: "memory");
  } else {
    STG_A_DMA(0, 0);
    STG_B(0, 0);
    STG_A_DMA(1, 1);
    STG_B(1, 1);
    asm volatile("s_waitcnt vmcnt(3)" ::: "memory");  // own stage-0 landed
  }
  __builtin_amdgcn_s_barrier();  // all waves' stage-0 certified
  __builtin_amdgcn_sched_barrier(0);
  {
    const char* ab0 = lds + wm * 4096 + pbase;
    const char* bb0 = lds + 16384 + wn * 4096 + pbase;
#pragma unroll
    for (int i = 0; i < 4; ++i) af[i] = *(const bf16x8*)(ab0 + i * 1024);
#pragma unroll
    for (int j = 0; j < 4; ++j) bs0[j] = *(const bf16x8*)(bb0 + j * 1024);
  }

#pragma unroll
  for (int sp = 0; sp < NKT / 2; ++sp) {
    STEP(2 * sp, bs0, bs1);
    STEP(2 * sp + 1, bs1, bs0);
  }
  __syncthreads();  // all waves done with LDS; reusable for epilogue

  // ---- epilogue: LDS-shuffled coalesced writeout (R4-verified) ----
  if (OUT_BF16) {
    unsigned short* tile = (unsigned short*)lds;  // 256 x 128 bf16 = 64 KiB
#pragma unroll
    for (int fi = 0; fi < 4; ++fi) {
#pragma unroll
      for (int cj = 0; cj < 4; ++cj) {
        int col = wn * 64 + cj * 16 + lrow;
        float bv = bias[bn0 + col];
#pragma unroll
        for (int r = 0; r < 4; ++r) {
          int row = wm * 64 + fi * 16 + kg * 4 + r;
          int sc = (((col >> 3) ^ (row & 7)) << 3) | (col & 7);
          tile[row * 128 + sc] = f2bf(acc[fi][cj][r] + bv);
        }
      }
    }
    __syncthreads();
#pragma unroll
    for (int it = 0; it < 8; ++it) {
      int id = it * 512 + tid;
      int row = id >> 4;  // 0..255 ; 16 x 16B chunks/row
      int c = id & 15;
      uint4 v = *(const uint4*)(lds + row * 256 + ((c ^ (row & 7)) << 4));
      *(uint4*)((unsigned short*)C + (size_t)(bm0 + row) * N + bn0 + c * 8) = v;
    }
  } else {
    float* tilef = (float*)lds;  // 128 x 128 f32 = 64 KiB per pass
#pragma unroll
    for (int pass = 0; pass < 2; ++pass) {
      if ((wm >> 1) == pass) {
#pragma unroll
        for (int fi = 0; fi < 4; ++fi) {
#pragma unroll
          for (int cj = 0; cj < 4; ++cj) {
            int col = wn * 64 + cj * 16 + lrow;
            float bv = bias[bn0 + col];
#pragma unroll
            for (int r = 0; r < 4; ++r) {
              int row = (wm & 1) * 64 + fi * 16 + kg * 4 + r;  // 0..127
              int sc = (((col >> 2) ^ (row & 7)) << 2) | (col & 3);
              tilef[row * 128 + sc] = acc[fi][cj][r] + bv;
            }
          }
        }
      }
      __syncthreads();
#pragma unroll
      for (int it = 0; it < 8; ++it) {
        int id = it * 512 + tid;
        int row = id >> 5;  // 0..127 ; 32 x 16B chunks/row
        int c = id & 31;
        uint4 v = *(const uint4*)(lds + row * 512 + ((c ^ (row & 7)) << 4));
        *(uint4*)((float*)C + (size_t)(bm0 + pass * 128 + row) * N + bn0 + c * 4) = v;
      }
      __syncthreads();
    }
  }
}

// ---------------- per-token attention, 1 token per wave ----------------
__global__ __launch_bounds__(256) void attn_tok(const __hip_bfloat16* __restrict__ qkv,
                                                __hip_bfloat16* __restrict__ outp,
                                                int ntok, int npb) {
  const int wv = threadIdx.x >> 6;
  const int ln = threadIdx.x & 63;
  const int t = blockIdx.x * 4 + wv;
  if (t >= ntok) return;
  const int m = ln & 7;

  const __hip_bfloat16* row = qkv + (size_t)t * 1536;
  uint4 qr = *(const uint4*)(row + ln * 8);
  uint4 kr = *(const uint4*)(row + 512 + ln * 8);
  uint4 vr = *(const uint4*)(row + 1024 + ln * 8);

  float qf[8];
  unpk2(qr.x, qf[0], qf[1]);
  unpk2(qr.y, qf[2], qf[3]);
  unpk2(qr.z, qf[4], qf[5]);
  unpk2(qr.w, qf[6], qf[7]);
  unsigned kw[4] = {kr.x, kr.y, kr.z, kr.w};
  unsigned vw[4] = {vr.x, vr.y, vr.z, vr.w};

  float dt[8];
#pragma unroll
  for (int g = 0; g < 8; ++g) {
    int src = g * 8 + m;
    float s = 0.f;
#pragma unroll
    for (int j4 = 0; j4 < 4; ++j4) {
      unsigned kk = __shfl(kw[j4], src, 64);
      float a, b;
      unpk2(kk, a, b);
      s += qf[j4 * 2] * a + qf[j4 * 2 + 1] * b;
    }
    s += __shfl_xor(s, 1, 64);
    s += __shfl_xor(s, 2, 64);
    s += __shfl_xor(s, 4, 64);
    dt[g] = s;
  }

  float mx = -1e30f;
#pragma unroll
  for (int g = 0; g < 8; ++g) {
    dt[g] = fminf(fmaxf(dt[g] * 0.125f, -50.f), 50.f);
    mx = fmaxf(mx, dt[g]);
  }
  float p[8], ssum = 0.f;
#pragma unroll
  for (int g = 0; g < 8; ++g) {
    p[g] = __expf(dt[g] - mx);
    ssum += p[g];
  }
  float inv = 1.f / ssum;

  float o[8] = {0, 0, 0, 0, 0, 0, 0, 0};
#pragma unroll
  for (int g = 0; g < 8; ++g) {
    int src = g * 8 + m;
    float ag = p[g] * inv;
#pragma unroll
    for (int j4 = 0; j4 < 4; ++j4) {
      unsigned vv = __shfl(vw[j4], src, 64);
      float a, b;
      unpk2(vv, a, b);
      o[j4 * 2] += ag * a;
      o[j4 * 2 + 1] += ag * b;
    }
  }

  const int h = ln >> 3;
  const int b = t / npb, n = t % npb;
  size_t dst = (size_t)b * npb * 512 + (size_t)(h * (npb >> 3) + (n >> 3)) * 512 +
               (size_t)((n & 7) * 64 + m * 8);
  uint4 ov;
  ov.x = pk2(o[0], o[1]);
  ov.y = pk2(o[2], o[3]);
  ov.z = pk2(o[4], o[5]);
  ov.w = pk2(o[6], o[7]);
  *(uint4*)(outp + dst) = ov;
}

// ---------------- launch ----------------
extern "C" void kernel_launch(void* const* d_in, const int* in_sizes, int n_in,
                              void* d_out, int out_size, void* d_ws, size_t ws_size,
                              hipStream_t stream) {
  const float* x = (const float*)d_in[0];
  const float* w_qkv = (const float*)d_in[1];
  const float* b_qkv = (const float*)d_in[2];
  const float* w_fc = (const float*)d_in[3];
  const float* b_fc = (const float*)d_in[4];
  float* out = (float*)d_out;

  const int M = 32768;
  const int Cc = 512, N3 = 1536;

  __hip_bfloat16* wqkvb = (__hip_bfloat16*)d_ws;
  __hip_bfloat16* wfcb = wqkvb + (size_t)N3 * Cc;
  __hip_bfloat16* qkvb = wfcb + (size_t)Cc * Cc;
  __hip_bfloat16* attb = qkvb + (size_t)M * N3;

  // weights only: (1536*512 + 512*512)/8 / 256 = 512 blocks
  cvt_w<<<512, 256, 0, stream>>>(w_qkv, w_fc, (unsigned short*)wqkvb, (unsigned short*)wfcb);

  // QKV: A = x (f32, fused convert); 128 x 12 = 1536 blocks
  gemmp<true, 512, true><<<(M / 256) * (N3 / 128), 512, 0, stream>>>(
      x, wqkvb, b_qkv, qkvb, M, N3, N3 / 128);
  attn_tok<<<M / 4, 256, 0, stream>>>(qkvb, attb, M, 8192);
  // FC: A = attb (bf16, DMA path); 128 x 4 = 512 blocks
  gemmp<false, 512, false><<<(M / 256) * (Cc / 128), 512, 0, stream>>>(
      attb, wfcb, b_fc, out, M, Cc, Cc / 128);
}